// Round 3
// baseline (106.185 us; speedup 1.0000x reference)
//
#include <hip/hip_runtime.h>
#include <hip/hip_bf16.h>

// Problem constants (fixed by the reference):
//   DIM=512 (embed width per axis), OUT_DIM=256, B=8, H=64, W=64.
// out[b,h,w,o] = A[h,o] + B[w,o], A = embed(arange(H)) @ W[:, :512]^T,
//                                 B = embed(arange(W)) @ W[:, 512:]^T
// embed(z)[d]      = sin(z * 1000^{-(2d+1)/512})   d in [0,256)
// embed(z)[256+d]  = cos(z * 1000^{-(2d)/512})     d in [0,256)
//
// Dtypes (established rounds 1-2): W_im is FLOAT32 (bf16 read -> NaN),
// d_out is FLOAT32 (8388608 floats; half-buffer bf16 write -> err 150.5
// matched the "read packed bf16 as f32" model exactly).

#define DIMC 512
#define ODIM 256
#define NPOS 64   // H == W == 64, same embed table for both axes

// Kernel 1: one block per position z (=h or w), thread t = output channel o.
// Builds embed vector e[512] in LDS (broadcast reads, conflict-free), then
// two 512-long fp32 dot products against fp32 W row o.
__global__ __launch_bounds__(256)
void pos_gemm_kernel(const float* __restrict__ Wim,
                     float* __restrict__ A, float* __restrict__ B) {
    __shared__ float e[DIMC];
    const int h = blockIdx.x;
    const int t = threadIdx.x;            // 0..255 = output channel o
    const float z = (float)h;
    const float ln1000 = 6.907755278982137f;

    // e[t] = sin part, e[256+t] = cos part
    float fs = __expf(-((float)(2 * t + 1) * (1.0f / 512.0f)) * ln1000);
    float fc = __expf(-((float)(2 * t)     * (1.0f / 512.0f)) * ln1000);
    e[t]       = sinf(z * fs);
    e[t + 256] = cosf(z * fc);
    __syncthreads();

    const float* wrow = Wim + (size_t)t * (2 * DIMC);   // 1024 floats
    float accA = 0.0f, accB = 0.0f;
#pragma unroll 4
    for (int d = 0; d < DIMC; d += 8) {
        float4 wa0 = *(const float4*)(wrow + d);
        float4 wa1 = *(const float4*)(wrow + d + 4);
        float4 wb0 = *(const float4*)(wrow + DIMC + d);
        float4 wb1 = *(const float4*)(wrow + DIMC + d + 4);
        float4 e0  = *(const float4*)(e + d);
        float4 e1  = *(const float4*)(e + d + 4);
        accA += wa0.x * e0.x + wa0.y * e0.y + wa0.z * e0.z + wa0.w * e0.w;
        accA += wa1.x * e1.x + wa1.y * e1.y + wa1.z * e1.z + wa1.w * e1.w;
        accB += wb0.x * e0.x + wb0.y * e0.y + wb0.z * e0.z + wb0.w * e0.w;
        accB += wb1.x * e1.x + wb1.y * e1.y + wb1.z * e1.z + wb1.w * e1.w;
    }
    A[h * ODIM + t] = accA;
    B[h * ODIM + t] = accB;
}

// Kernel 2: broadcast add, fp32 out. One thread = 4 consecutive f32 outputs
// (float4, 16B coalesced store). flat = ((b*64+h)*64+w)*256 + o;
// t*4 = b*2^20 + h*2^14 + w*2^8 + o4.
__global__ __launch_bounds__(256)
void pos_bcast_kernel(const float* __restrict__ A, const float* __restrict__ B,
                      float* __restrict__ out) {
    const int t = blockIdx.x * 256 + threadIdx.x;   // 0 .. 2097151
    const int o4 = (t & 63) << 2;                   // o in {0,4,...,252}
    const int w  = (t >> 6) & 63;
    const int h  = (t >> 12) & 63;                  // b = t >> 18 (value-independent)

    float4 a = *(const float4*)(A + h * ODIM + o4);
    float4 b = *(const float4*)(B + w * ODIM + o4);
    float4 r;
    r.x = a.x + b.x;
    r.y = a.y + b.y;
    r.z = a.z + b.z;
    r.w = a.w + b.w;
    *(float4*)(out + (size_t)t * 4) = r;
}

extern "C" void kernel_launch(void* const* d_in, const int* in_sizes, int n_in,
                              void* d_out, int out_size, void* d_ws, size_t ws_size,
                              hipStream_t stream) {
    const float* Wim = (const float*)d_in[0];   // fp32, 256 x 1024
    float* A = (float*)d_ws;                    // 64*256 fp32
    float* B = A + NPOS * ODIM;                 // 64*256 fp32 (128 KB ws total)
    float* out = (float*)d_out;

    pos_gemm_kernel<<<NPOS, 256, 0, stream>>>(Wim, A, B);
    // 8*64*64*256 = 8388608 f32 outputs, 4 per thread -> 2097152 threads
    pos_bcast_kernel<<<8192, 256, 0, stream>>>(A, B, out);
}

// Round 4
// 85.247 us; speedup vs baseline: 1.2456x; 1.2456x over previous
//
#include <hip/hip_runtime.h>
#include <hip/hip_bf16.h>

// Problem constants (fixed by the reference):
//   DIM=512 (embed width per axis), OUT_DIM=256, B=8, H=64, W=64.
// Separable: out[b,h,w,o] = A[h,o] + B[w,o],
//   A = embed(arange(64)) @ W[:, :512]^T,  B = embed(arange(64)) @ W[:, 512:]^T
// embed(z)[d]      = sin(z * 1000^{-(2d+1)/512})   d in [0,256)
// embed(z)[256+d]  = cos(z * 1000^{-(2d)/512})     d in [0,256)
//
// Dtypes (established rounds 1-3): W_im fp32 in, d_out fp32 (8388608 floats).
// absmax=0.5 at round 3 == one bf16 ulp at |out|~106: the harness compares
// after bf16 cast; fp32 compute is well inside the 2.12 threshold.

#define ODIM 256
#define NPOS 64
#define KQ   128   // K-quarter (512 / 4)

// Kernel 1: 256 blocks = (h, K-quarter q). Thread t = output channel o.
// Each block builds its 128-entry slice of the embed vector in LDS, then
// every thread does two 128-long partial dots against its W row.
// Plain stores of partials -> no atomics, no dependence on ws init state.
__global__ __launch_bounds__(256)
void pos_gemm_kernel(const float* __restrict__ Wim,
                     float* __restrict__ Apart, float* __restrict__ Bpart) {
    __shared__ float e[KQ];
    const int h = blockIdx.x >> 2;
    const int q = blockIdx.x & 3;
    const int t = threadIdx.x;            // 0..255 = output channel o
    const int kbase = q * KQ;

    if (t < KQ) {
        const float ln1000 = 6.907755278982137f;
        const float z = (float)h;
        const int k = kbase + t;
        float v;
        if (k < 256) {                    // sin half: freq exp -(2k+1)/512
            float f = __expf(-((float)(2 * k + 1) * (1.0f / 512.0f)) * ln1000);
            v = sinf(z * f);
        } else {                          // cos half: freq exp -(2j)/512
            int j = k - 256;
            float f = __expf(-((float)(2 * j) * (1.0f / 512.0f)) * ln1000);
            v = cosf(z * f);
        }
        e[t] = v;
    }
    __syncthreads();

    const float* wA = Wim + (size_t)t * 1024 + kbase;   // W[o, kbase..]
    const float* wB = wA + 512;                          // W[o, 512+kbase..]
    float accA = 0.0f, accB = 0.0f;
#pragma unroll 4
    for (int d = 0; d < KQ; d += 8) {
        float4 a0 = *(const float4*)(wA + d);
        float4 a1 = *(const float4*)(wA + d + 4);
        float4 b0 = *(const float4*)(wB + d);
        float4 b1 = *(const float4*)(wB + d + 4);
        float4 e0 = *(const float4*)(e + d);             // broadcast, conflict-free
        float4 e1 = *(const float4*)(e + d + 4);
        accA += a0.x * e0.x + a0.y * e0.y + a0.z * e0.z + a0.w * e0.w;
        accA += a1.x * e1.x + a1.y * e1.y + a1.z * e1.z + a1.w * e1.w;
        accB += b0.x * e0.x + b0.y * e0.y + b0.z * e0.z + b0.w * e0.w;
        accB += b1.x * e1.x + b1.y * e1.y + b1.z * e1.z + b1.w * e1.w;
    }
    Apart[q * (NPOS * ODIM) + h * ODIM + t] = accA;
    Bpart[q * (NPOS * ODIM) + h * ODIM + t] = accB;
}

// Kernel 2: 1024 blocks = (h, w-tile of 4). Thread t -> (w_in_tile, o4).
// Sums the 4 K-partials (L2-resident) and stores the result for all 8
// batch copies (8 coalesced float4 bursts per wave).
__global__ __launch_bounds__(256)
void pos_bcast_kernel(const float* __restrict__ Apart,
                      const float* __restrict__ Bpart,
                      float* __restrict__ out) {
    const int h  = blockIdx.x >> 4;
    const int wt = blockIdx.x & 15;
    const int t  = threadIdx.x;
    const int o4 = (t & 63) << 2;          // o in {0,4,...,252}
    const int w  = wt * 4 + (t >> 6);

    const int ai = h * ODIM + o4;
    const int bi = w * ODIM + o4;
    float4 r = make_float4(0.f, 0.f, 0.f, 0.f);
#pragma unroll
    for (int q = 0; q < 4; ++q) {
        float4 a = *(const float4*)(Apart + q * (NPOS * ODIM) + ai);
        float4 b = *(const float4*)(Bpart + q * (NPOS * ODIM) + bi);
        r.x += a.x + b.x;
        r.y += a.y + b.y;
        r.z += a.z + b.z;
        r.w += a.w + b.w;
    }

    const int base = (h << 14) | (w << 8) | o4;   // ((h*64)+w)*256 + o4
#pragma unroll
    for (int b = 0; b < 8; ++b) {
        *(float4*)(out + (size_t)((b << 20) | base)) = r;
    }
}

extern "C" void kernel_launch(void* const* d_in, const int* in_sizes, int n_in,
                              void* d_out, int out_size, void* d_ws, size_t ws_size,
                              hipStream_t stream) {
    const float* Wim = (const float*)d_in[0];        // fp32, 256 x 1024
    float* Apart = (float*)d_ws;                     // 4 * 64*256 fp32 (256 KB)
    float* Bpart = Apart + 4 * NPOS * ODIM;          // 4 * 64*256 fp32 (256 KB)
    float* out = (float*)d_out;

    pos_gemm_kernel<<<NPOS * 4, 256, 0, stream>>>(Wim, Apart, Bpart);
    pos_bcast_kernel<<<NPOS * 16, 256, 0, stream>>>(Apart, Bpart, out);
}